// Round 4
// baseline (78.272 us; speedup 1.0000x reference)
//
#include <hip/hip_runtime.h>
#include <math.h>

#define BM 60      // modes per batch
#define TT 80      // timesteps
#define NAG 128    // agents
#define NLANES 64
#define NPTS 20
#define NLP (NLANES * NPTS)  // 1280 lane points
#define PPL (NLP / 64)       // 20 lane-points per lane
#define APL (NAG / 64)       // 2 agents per lane

// One block of 4 waves per (b,m); wave w handles t in [20w, 20w+20), tiled 5.
// Points register-resident with distance expansion:
//   d^2 = c_t + s,  s = q_p - 2*ex*px - 2*ey*py,  q_p = px^2+py^2
// inner eval = fma,fma,fmin; thresholds fold into 4-c_t / 9-c_t.
__global__ __launch_bounds__(256) void score_kernel(
    const float* __restrict__ trajs,   // (B, M, T, 3)
    const float* __restrict__ agents,  // (B, NAG, 4)
    const float* __restrict__ amask,   // (B, NAG)
    const float* __restrict__ lanes,   // (B, NLANES, NPTS, 3)
    const float* __restrict__ lmask,   // (B, NLANES)
    float* __restrict__ scores)        // (B*M,)
{
    __shared__ float s_ex[TT], s_ey[TT];
    __shared__ float s_j[2];
    __shared__ float s_cc[4], s_cd[4];

    const int bm   = blockIdx.x;       // b*M + m
    const int b    = bm / BM;
    const int tid  = threadIdx.x;      // 0..255
    const int w    = tid >> 6;         // wave 0..3
    const int lane = tid & 63;

    const float* tr = trajs + (size_t)bm * TT * 3;
    for (int i = tid; i < TT; i += 256) {
        s_ex[i] = tr[i * 3 + 0];
        s_ey[i] = tr[i * 3 + 1];
    }

    // Lane-private points; mask folded into x (+1e8 => s ~ 1e16, never passes
    // either threshold — same booleans as reference's +1e6 distance penalty).
    float ax[APL], ay[APL], aq[APL];
#pragma unroll
    for (int k = 0; k < APL; ++k) {
        const int i = lane + 64 * k;
        const float off = (1.0f - amask[b * NAG + i]) * 1e8f;
        const float x = agents[((size_t)b * NAG + i) * 4 + 0] + off;
        const float y = agents[((size_t)b * NAG + i) * 4 + 1];
        ax[k] = x; ay[k] = y; aq[k] = fmaf(x, x, y * y);
    }
    float px[PPL], py[PPL], pq[PPL];
#pragma unroll
    for (int k = 0; k < PPL; ++k) {
        const int i = lane + 64 * k;
        const float off = (1.0f - lmask[b * NLANES + i / NPTS]) * 1e8f;
        const float x = lanes[((size_t)b * NLP + i) * 3 + 0] + off;
        const float y = lanes[((size_t)b * NLP + i) * 3 + 1];
        px[k] = x; py[k] = y; pq[k] = fmaf(x, x, y * y);
    }

    __syncthreads();

    // comfort: jerk[t] = x[t+3] - 3x[t+2] + 3x[t+1] - x[t], t in [0,77)
    // handled by waves 0 and 1 (tid < 77), shuffle-reduced per wave.
    float jsum = 0.0f;
    if (tid < TT - 3) {
        const float jx = s_ex[tid + 3] - 3.0f * s_ex[tid + 2] + 3.0f * s_ex[tid + 1] - s_ex[tid];
        const float jy = s_ey[tid + 3] - 3.0f * s_ey[tid + 2] + 3.0f * s_ey[tid + 1] - s_ey[tid];
        jsum = sqrtf(jx * jx + jy * jy);
    }
    for (int off = 32; off > 0; off >>= 1) jsum += __shfl_xor(jsum, off, 64);
    if (w < 2 && lane == 0) s_j[w] = jsum;

    int ccoll = 0, cdriv = 0;
    const int t0 = w * (TT / 4);
    for (int r = 0; r < 4; ++r) {
        const int tb = t0 + r * 5;
        float mx5[5], my5[5], thrA[5], thrB[5], m2[5], m3[5];
#pragma unroll
        for (int j = 0; j < 5; ++j) {
            const float ex = s_ex[tb + j];   // broadcast read
            const float ey = s_ey[tb + j];
            const float c  = fmaf(ex, ex, ey * ey);
            mx5[j]  = -2.0f * ex;
            my5[j]  = -2.0f * ey;
            thrA[j] = 4.0f - c;
            thrB[j] = 9.0f - c;
            m2[j] = 1e30f;
            m3[j] = 1e30f;
        }
#pragma unroll
        for (int k = 0; k < APL; ++k) {
#pragma unroll
            for (int j = 0; j < 5; ++j) {
                float v = fmaf(my5[j], ay[k], aq[k]);
                v = fmaf(mx5[j], ax[k], v);
                m2[j] = fminf(m2[j], v);
            }
        }
#pragma unroll
        for (int k = 0; k < PPL; ++k) {
#pragma unroll
            for (int j = 0; j < 5; ++j) {
                float v = fmaf(my5[j], py[k], pq[k]);
                v = fmaf(mx5[j], px[k], v);
                m3[j] = fminf(m3[j], v);
            }
        }
#pragma unroll
        for (int j = 0; j < 5; ++j) {
            // min d^2 < 4  <=> exists s < 4-c ; min d^2 > 9 <=> no s <= 9-c
            ccoll += (__ballot(m2[j] < thrA[j]) != 0ull) ? 1 : 0;
            cdriv += (__ballot(m3[j] <= thrB[j]) == 0ull) ? 1 : 0;
        }
    }
    if (lane == 0) { s_cc[w] = (float)ccoll; s_cd[w] = (float)cdriv; }
    __syncthreads();

    if (tid == 0) {
        const float coll = s_cc[0] + s_cc[1] + s_cc[2] + s_cc[3];
        const float driv = s_cd[0] + s_cd[1] + s_cd[2] + s_cd[3];
        const float comfort  = -((s_j[0] + s_j[1]) / (float)(TT - 3));
        const float progress = tr[(TT - 1) * 3 + 0];
        scores[bm] = 0.1f * comfort + 0.5f * progress
                   - 1.0f * (coll / (float)TT)
                   - 0.3f * (driv / (float)TT);
    }
}

// Per-b softmax over M=60 logits, add partial scores, argmax (first-index
// tie-break like jnp.argmax), emit winning trajectory + index.
__global__ __launch_bounds__(64) void select_kernel(
    const float* __restrict__ logits,  // (B, M)
    const float* __restrict__ trajs,   // (B, M, T, 3)
    const float* __restrict__ scores,  // (B*M,)
    float* __restrict__ out,           // traj (B*T*3) then idx (B)
    int B)
{
    const int b    = blockIdx.x;
    const int lane = threadIdx.x;

    float lg = (lane < BM) ? logits[b * BM + lane] : -1e30f;
    float mx = lg;
    for (int off = 32; off > 0; off >>= 1) mx = fmaxf(mx, __shfl_xor(mx, off, 64));
    float e = (lane < BM) ? expf(lg - mx) : 0.0f;
    float sum = e;
    for (int off = 32; off > 0; off >>= 1) sum += __shfl_xor(sum, off, 64);

    float sc = (lane < BM) ? (e / sum + scores[b * BM + lane]) : -1e30f;
    int idx = lane;
    for (int off = 32; off > 0; off >>= 1) {
        float os = __shfl_xor(sc, off, 64);
        int   oi = __shfl_xor(idx, off, 64);
        if (os > sc || (os == sc && oi < idx)) { sc = os; idx = oi; }
    }
    const float* src = trajs + ((size_t)b * BM + idx) * TT * 3;
    for (int k = lane; k < TT * 3; k += 64) out[b * TT * 3 + k] = src[k];
    if (lane == 0) out[B * TT * 3 + b] = (float)idx;
}

extern "C" void kernel_launch(void* const* d_in, const int* in_sizes, int n_in,
                              void* d_out, int out_size, void* d_ws, size_t ws_size,
                              hipStream_t stream) {
    const float* logits = (const float*)d_in[0];
    const float* trajs  = (const float*)d_in[1];
    const float* agents = (const float*)d_in[2];
    const float* amask  = (const float*)d_in[3];
    const float* lanes  = (const float*)d_in[4];
    const float* lmask  = (const float*)d_in[5];

    const int B = in_sizes[0] / BM;  // 16
    float* scores = (float*)d_ws;    // B*M floats of scratch
    float* out    = (float*)d_out;

    score_kernel<<<B * BM, 256, 0, stream>>>(trajs, agents, amask, lanes, lmask, scores);
    select_kernel<<<B, 64, 0, stream>>>(logits, trajs, scores, out, B);
}

// Round 5
// 78.257 us; speedup vs baseline: 1.0002x; 1.0002x over previous
//
#include <hip/hip_runtime.h>
#include <math.h>

#define BM 60      // modes per batch
#define TT 80      // timesteps
#define NAG 128    // agents
#define NLANES 64
#define NPTS 20
#define NLP (NLANES * NPTS)  // 1280 lane points
#define PPL (NLP / 64)       // 20 lane-points per lane
#define APL (NAG / 64)       // 2 agents per lane

// One block of 4 waves per (b,m); wave w handles t in [20w, 20w+20), tiled 5.
// Staging is fully coalesced (float4 -> LDS raw); hot loop register-resident.
// Distance expansion: d^2 = c_t + s, s = q_p - 2*ex*px - 2*ey*py,
// q_p = px^2+py^2 + (1-mask)*1e8 (mask folded into q; |2 e.p| << 1e8 so the
// threshold booleans match the reference's +1e6-on-distance penalty).
__global__ __launch_bounds__(256) void score_kernel(
    const float* __restrict__ trajs,   // (B, M, T, 3)
    const float* __restrict__ agents,  // (B, NAG, 4)
    const float* __restrict__ amask,   // (B, NAG)
    const float* __restrict__ lanes,   // (B, NLANES, NPTS, 3)
    const float* __restrict__ lmask,   // (B, NLANES)
    float* __restrict__ scores)        // (B*M,)
{
    __shared__ __align__(16) float s_ln[NLP * 3];  // raw (x,y,z) lane points
    __shared__ __align__(16) float s_tr[TT * 3];   // raw ego trajectory
    __shared__ float s_lm[NLANES];
    __shared__ float s_j[2];
    __shared__ float s_cc[4], s_cd[4];

    const int bm   = blockIdx.x;       // b*M + m
    const int b    = bm / BM;
    const int tid  = threadIdx.x;      // 0..255
    const int w    = tid >> 6;         // wave 0..3
    const int lane = tid & 63;

    // ---- coalesced staging ----
    const float4* gl4 = (const float4*)(lanes + (size_t)b * NLP * 3);
    float4* sl4 = (float4*)s_ln;
    for (int i = tid; i < (NLP * 3) / 4; i += 256) sl4[i] = gl4[i];  // 960 f4

    const float4* gt4 = (const float4*)(trajs + (size_t)bm * TT * 3);
    if (tid < (TT * 3) / 4) ((float4*)s_tr)[tid] = gt4[tid];         // 60 f4

    if (tid < NLANES) s_lm[tid] = lmask[b * NLANES + tid];

    // agents: 16-byte records, directly coalesced float4; no LDS round-trip
    float ax[APL], ay[APL], aq[APL];
    const float4* ga4 = (const float4*)(agents + (size_t)b * NAG * 4);
#pragma unroll
    for (int k = 0; k < APL; ++k) {
        const int i = k * 64 + lane;
        const float4 a = ga4[i];
        const float moff = (1.0f - amask[b * NAG + i]) * 1e8f;
        ax[k] = a.x; ay[k] = a.y;
        aq[k] = fmaf(a.x, a.x, a.y * a.y) + moff;
    }

    __syncthreads();

    // per-lane lane-points from LDS into registers (2-way bank aliasing: free)
    float px[PPL], py[PPL], pq[PPL];
#pragma unroll
    for (int k = 0; k < PPL; ++k) {
        const int p = k * 64 + lane;
        const float x = s_ln[3 * p];
        const float y = s_ln[3 * p + 1];
        const float moff = (1.0f - s_lm[p / NPTS]) * 1e8f;
        px[k] = x; py[k] = y;
        pq[k] = fmaf(x, x, y * y) + moff;
    }

    // comfort: jerk[t] = x[t+3] - 3x[t+2] + 3x[t+1] - x[t], t in [0,77)
    float jsum = 0.0f;
    if (tid < TT - 3) {
        const float jx = s_tr[3 * (tid + 3)]     - 3.0f * s_tr[3 * (tid + 2)]
                       + 3.0f * s_tr[3 * (tid + 1)]     - s_tr[3 * tid];
        const float jy = s_tr[3 * (tid + 3) + 1] - 3.0f * s_tr[3 * (tid + 2) + 1]
                       + 3.0f * s_tr[3 * (tid + 1) + 1] - s_tr[3 * tid + 1];
        jsum = sqrtf(jx * jx + jy * jy);
    }
    for (int off = 32; off > 0; off >>= 1) jsum += __shfl_xor(jsum, off, 64);
    if (w < 2 && lane == 0) s_j[w] = jsum;

    int ccoll = 0, cdriv = 0;
    const int t0 = w * (TT / 4);
    for (int r = 0; r < 4; ++r) {
        const int tb = t0 + r * 5;
        float mx5[5], my5[5], thrA[5], thrB[5], m2[5], m3[5];
#pragma unroll
        for (int j = 0; j < 5; ++j) {
            const float ex = s_tr[3 * (tb + j)];      // broadcast read
            const float ey = s_tr[3 * (tb + j) + 1];
            const float c  = fmaf(ex, ex, ey * ey);
            mx5[j]  = -2.0f * ex;
            my5[j]  = -2.0f * ey;
            thrA[j] = 4.0f - c;
            thrB[j] = 9.0f - c;
            m2[j] = 1e30f;
            m3[j] = 1e30f;
        }
#pragma unroll
        for (int k = 0; k < APL; ++k) {
#pragma unroll
            for (int j = 0; j < 5; ++j) {
                float v = fmaf(my5[j], ay[k], aq[k]);
                v = fmaf(mx5[j], ax[k], v);
                m2[j] = fminf(m2[j], v);
            }
        }
#pragma unroll
        for (int k = 0; k < PPL; ++k) {
#pragma unroll
            for (int j = 0; j < 5; ++j) {
                float v = fmaf(my5[j], py[k], pq[k]);
                v = fmaf(mx5[j], px[k], v);
                m3[j] = fminf(m3[j], v);
            }
        }
#pragma unroll
        for (int j = 0; j < 5; ++j) {
            // min d^2 < 4  <=> exists s < 4-c ; min d^2 > 9 <=> no s <= 9-c
            ccoll += (__ballot(m2[j] < thrA[j]) != 0ull) ? 1 : 0;
            cdriv += (__ballot(m3[j] <= thrB[j]) == 0ull) ? 1 : 0;
        }
    }
    if (lane == 0) { s_cc[w] = (float)ccoll; s_cd[w] = (float)cdriv; }
    __syncthreads();

    if (tid == 0) {
        const float coll = s_cc[0] + s_cc[1] + s_cc[2] + s_cc[3];
        const float driv = s_cd[0] + s_cd[1] + s_cd[2] + s_cd[3];
        const float comfort  = -((s_j[0] + s_j[1]) / (float)(TT - 3));
        const float progress = s_tr[(TT - 1) * 3];
        scores[bm] = 0.1f * comfort + 0.5f * progress
                   - 1.0f * (coll / (float)TT)
                   - 0.3f * (driv / (float)TT);
    }
}

// Per-b softmax over M=60 logits, add partial scores, argmax (first-index
// tie-break like jnp.argmax), emit winning trajectory + index.
__global__ __launch_bounds__(64) void select_kernel(
    const float* __restrict__ logits,  // (B, M)
    const float* __restrict__ trajs,   // (B, M, T, 3)
    const float* __restrict__ scores,  // (B*M,)
    float* __restrict__ out,           // traj (B*T*3) then idx (B)
    int B)
{
    const int b    = blockIdx.x;
    const int lane = threadIdx.x;

    float lg = (lane < BM) ? logits[b * BM + lane] : -1e30f;
    float mx = lg;
    for (int off = 32; off > 0; off >>= 1) mx = fmaxf(mx, __shfl_xor(mx, off, 64));
    float e = (lane < BM) ? expf(lg - mx) : 0.0f;
    float sum = e;
    for (int off = 32; off > 0; off >>= 1) sum += __shfl_xor(sum, off, 64);

    float sc = (lane < BM) ? (e / sum + scores[b * BM + lane]) : -1e30f;
    int idx = lane;
    for (int off = 32; off > 0; off >>= 1) {
        float os = __shfl_xor(sc, off, 64);
        int   oi = __shfl_xor(idx, off, 64);
        if (os > sc || (os == sc && oi < idx)) { sc = os; idx = oi; }
    }
    const float* src = trajs + ((size_t)b * BM + idx) * TT * 3;
    for (int k = lane; k < TT * 3; k += 64) out[b * TT * 3 + k] = src[k];
    if (lane == 0) out[B * TT * 3 + b] = (float)idx;
}

extern "C" void kernel_launch(void* const* d_in, const int* in_sizes, int n_in,
                              void* d_out, int out_size, void* d_ws, size_t ws_size,
                              hipStream_t stream) {
    const float* logits = (const float*)d_in[0];
    const float* trajs  = (const float*)d_in[1];
    const float* agents = (const float*)d_in[2];
    const float* amask  = (const float*)d_in[3];
    const float* lanes  = (const float*)d_in[4];
    const float* lmask  = (const float*)d_in[5];

    const int B = in_sizes[0] / BM;  // 16
    float* scores = (float*)d_ws;    // B*M floats of scratch
    float* out    = (float*)d_out;

    score_kernel<<<B * BM, 256, 0, stream>>>(trajs, agents, amask, lanes, lmask, scores);
    select_kernel<<<B, 64, 0, stream>>>(logits, trajs, scores, out, B);
}